// Round 7
// baseline (23828.015 us; speedup 1.0000x reference)
//
#include <hip/hip_runtime.h>
#include <math.h>

// LSTM forward: T=1024, B=64, I=256, H=512 (4H=2048), fp32.
// Round 7: persistent kernel (R6's verified sync) + software pipeline:
//   * x_{t+1}: global-load at head (hidden under h-FMA), LDS-staged pre-S1,
//     x-partials computed AFTER arrive / BEFORE spin (spin absorbs them)
//   * conflict-free staging: wave wv owns row wv, lane -> f4 #lane
//   * all-wave spin, then each wave loads its own h row (sc0 sc1 bypass)
//   * assembly merged into update (no gbuf, one less sync); red padded to 68
//   * fast tanh via __expf
// block = (rg: 8 rows) x (cg: 16 cells = 64 gate cols); 256 blocks x 512 thr.
// weights: 96 f32/thread in VGPRs; c LDS-resident; h chains through d_out.

#define TT      1024
#define BB      64
#define II      256
#define HH      512
#define G4H     2048
#define RPB     8
#define CPB     16
#define NCG     32
#define NRG     8
#define THREADS 512

__device__ __forceinline__ void coh_load2_f4(const float* p0, const float* p1,
                                             float4& a, float4& b) {
    asm volatile(
        "global_load_dwordx4 %0, %2, off sc0 sc1\n\t"
        "global_load_dwordx4 %1, %3, off sc0 sc1\n\t"
        "s_waitcnt vmcnt(0)"
        : "=&v"(a), "=&v"(b)
        : "v"(p0), "v"(p1)
        : "memory");
}
__device__ __forceinline__ void coh_store_f(float* p, float v) {
    asm volatile("global_store_dword %0, %1, off sc0 sc1"
                 :: "v"(p), "v"(v) : "memory");
}
__device__ __forceinline__ float fast_tanh(float v) {
    const float e = __expf(-2.0f * fabsf(v));
    const float r = (1.0f - e) / (1.0f + e);
    return v < 0.0f ? -r : r;
}

__global__ void init_ctr(unsigned int* ctr) { ctr[threadIdx.x] = 0; }

__global__ __launch_bounds__(THREADS, 2) void lstm_persist(
    const float* __restrict__ x,    // [T][B][I]
    const float* __restrict__ Wi,   // [I][4H]
    const float* __restrict__ Wh,   // [H][4H]
    const float* __restrict__ bi,   // [4H]
    const float* __restrict__ bh,   // [4H]
    const float* __restrict__ h0,   // [B][H]
    const float* __restrict__ c0,   // [B][H]
    float* __restrict__ out,        // [T][B][H]
    unsigned int* __restrict__ ctr) // [NRG*32], pre-zeroed
{
    const int tid   = threadIdx.x;
    const int cg    = blockIdx.x & 31;
    const int rg    = blockIdx.x >> 5;
    const int row0  = rg * RPB;
    const int cell0 = cg * CPB;

    const int lane   = tid & 63;
    const int wv     = tid >> 6;
    const int colgrp = lane & 31;
    const int kc     = wv * 2 + (lane >> 5);   // k chunk 0..15

    const int bcA = colgrp, bcB = colgrp + 32;
    const int JA  = (bcA >> 4) * HH + cell0 + (bcA & 15);
    const int JB  = (bcB >> 4) * HH + cell0 + (bcB & 15);

    __shared__ float xbuf[RPB][II];        // 8 KB
    __shared__ float hbuf[RPB][HH];        // 16 KB
    __shared__ float red[8][RPB][68];      // 17.4 KB (padded)
    __shared__ float c_lds[RPB][CPB];      // 512 B, persistent

    // ---- one-time: weights -> VGPRs (2 cols x (16 x-k + 32 h-k)) ----
    float4 wxA[4], wxB[4], whA[8], whB[8];
    #pragma unroll
    for (int q = 0; q < 4; ++q) {
        float ta[4], tb[4];
        #pragma unroll
        for (int e = 0; e < 4; ++e) {
            const int k = kc * 16 + q * 4 + e;
            ta[e] = Wi[(size_t)k * G4H + JA];
            tb[e] = Wi[(size_t)k * G4H + JB];
        }
        wxA[q] = make_float4(ta[0], ta[1], ta[2], ta[3]);
        wxB[q] = make_float4(tb[0], tb[1], tb[2], tb[3]);
    }
    #pragma unroll
    for (int q = 0; q < 8; ++q) {
        float ta[4], tb[4];
        #pragma unroll
        for (int e = 0; e < 4; ++e) {
            const int k = kc * 32 + q * 4 + e;
            ta[e] = Wh[(size_t)k * G4H + JA];
            tb[e] = Wh[(size_t)k * G4H + JB];
        }
        whA[q] = make_float4(ta[0], ta[1], ta[2], ta[3]);
        whB[q] = make_float4(tb[0], tb[1], tb[2], tb[3]);
    }

    // update-role constants (threads 0..127): r = tid>>4, m = tid&15
    float b4[4];
    if (tid < RPB * CPB) {
        const int m = tid & 15;
        #pragma unroll
        for (int G = 0; G < 4; ++G)
            b4[G] = bi[G * HH + cell0 + m] + bh[G * HH + cell0 + m];
        c_lds[tid >> 4][m] = c0[(size_t)(row0 + (tid >> 4)) * HH + cell0 + m];
    }

    unsigned int* myctr = ctr + rg * 32;

    // ---- prologue: stage x_0 and h0, compute x-partials for t=0 ----
    {
        xbuf[wv][lane] = 0.f;  // touch to keep layout; real fill below
        const float4 xv = ((const float4*)(x + (size_t)(row0 + wv) * II))[lane];
        ((float4*)&xbuf[wv][0])[lane] = xv;
        const float4* hs = (const float4*)(h0 + (size_t)(row0 + wv) * HH);
        ((float4*)&hbuf[wv][0])[lane]      = hs[lane];
        ((float4*)&hbuf[wv][0])[lane + 64] = hs[lane + 64];
    }
    __syncthreads();

    float xaccA[RPB], xaccB[RPB];
    {
        const float4* xv4 = ((const float4*)&xbuf[0][0]) + kc * 4;
        #pragma unroll
        for (int r = 0; r < RPB; ++r) { xaccA[r] = 0.f; xaccB[r] = 0.f; }
        #pragma unroll
        for (int q = 0; q < 4; ++q) {
            const float4 wa = wxA[q], wb = wxB[q];
            #pragma unroll
            for (int r = 0; r < RPB; ++r) {
                const float4 a = xv4[r * 64 + q];
                xaccA[r] = fmaf(a.x, wa.x, xaccA[r]);
                xaccA[r] = fmaf(a.y, wa.y, xaccA[r]);
                xaccA[r] = fmaf(a.z, wa.z, xaccA[r]);
                xaccA[r] = fmaf(a.w, wa.w, xaccA[r]);
                xaccB[r] = fmaf(a.x, wb.x, xaccB[r]);
                xaccB[r] = fmaf(a.y, wb.y, xaccB[r]);
                xaccB[r] = fmaf(a.z, wb.z, xaccB[r]);
                xaccB[r] = fmaf(a.w, wb.w, xaccB[r]);
            }
        }
    }
    __syncthreads();

    for (int t = 0; t < TT; ++t) {
        const bool more = (t + 1 < TT);

        // ---- issue x_{t+1} load early (latency hidden under h-FMA) ----
        float4 xnext;
        if (more)
            xnext = ((const float4*)(x + ((size_t)(t + 1) * BB + row0 + wv) * II))[lane];

        // ---- h-FMA: acc starts from x-partials ----
        float accA[RPB], accB[RPB];
        #pragma unroll
        for (int r = 0; r < RPB; ++r) { accA[r] = xaccA[r]; accB[r] = xaccB[r]; }
        {
            const float4* hv4 = ((const float4*)&hbuf[0][0]) + kc * 8;
            #pragma unroll
            for (int q = 0; q < 8; ++q) {
                const float4 wa = whA[q], wb = whB[q];
                #pragma unroll
                for (int r = 0; r < RPB; ++r) {
                    const float4 a = hv4[r * 128 + q];
                    accA[r] = fmaf(a.x, wa.x, accA[r]);
                    accA[r] = fmaf(a.y, wa.y, accA[r]);
                    accA[r] = fmaf(a.z, wa.z, accA[r]);
                    accA[r] = fmaf(a.w, wa.w, accA[r]);
                    accB[r] = fmaf(a.x, wb.x, accB[r]);
                    accB[r] = fmaf(a.y, wb.y, accB[r]);
                    accB[r] = fmaf(a.z, wb.z, accB[r]);
                    accB[r] = fmaf(a.w, wb.w, accB[r]);
                }
            }
        }

        // ---- stage x_{t+1} (conflict-free: lane -> f4 #lane) ----
        if (more) ((float4*)&xbuf[wv][0])[lane] = xnext;

        // ---- wave reduce (pair kc, kc^1 at lane^32) + red writes ----
        #pragma unroll
        for (int r = 0; r < RPB; ++r) {
            accA[r] += __shfl_xor(accA[r], 32, 64);
            accB[r] += __shfl_xor(accB[r], 32, 64);
        }
        if (lane < 32) {
            #pragma unroll
            for (int r = 0; r < RPB; ++r) {
                red[wv][r][colgrp]      = accA[r];
                red[wv][r][colgrp + 32] = accB[r];
            }
        }
        __syncthreads();                       // S1

        // ---- assembly + cell update (threads 0..127) ----
        if (tid < RPB * CPB) {
            const int r = tid >> 4, m = tid & 15;
            float gate[4];
            #pragma unroll
            for (int G = 0; G < 4; ++G) {
                float s = b4[G];
                #pragma unroll
                for (int p = 0; p < 8; ++p) s += red[p][r][G * 16 + m];
                gate[G] = s;
            }
            const float ig = 1.0f / (1.0f + __expf(-gate[0]));
            const float fg = 1.0f / (1.0f + __expf(-gate[1]));
            const float gg = fast_tanh(gate[2]);
            const float og = 1.0f / (1.0f + __expf(-gate[3]));
            const float cn = fg * c_lds[r][m] + ig * gg;
            c_lds[r][m] = cn;
            const size_t idx = ((size_t)t * BB + row0 + r) * HH + cell0 + m;
            coh_store_f(out + idx, og * fast_tanh(cn));
        }

        // ---- drain h stores, then arrive ----
        asm volatile("s_waitcnt vmcnt(0) lgkmcnt(0)" ::: "memory");
        __syncthreads();                       // S2
        if (more) {
            if (tid == 0)
                __hip_atomic_fetch_add(myctr, 1u, __ATOMIC_RELAXED,
                                       __HIP_MEMORY_SCOPE_AGENT);

            // ---- x-partials for t+1 (absorbs peer skew before spin) ----
            const float4* xv4 = ((const float4*)&xbuf[0][0]) + kc * 4;
            #pragma unroll
            for (int r = 0; r < RPB; ++r) { xaccA[r] = 0.f; xaccB[r] = 0.f; }
            #pragma unroll
            for (int q = 0; q < 4; ++q) {
                const float4 wa = wxA[q], wb = wxB[q];
                #pragma unroll
                for (int r = 0; r < RPB; ++r) {
                    const float4 a = xv4[r * 64 + q];
                    xaccA[r] = fmaf(a.x, wa.x, xaccA[r]);
                    xaccA[r] = fmaf(a.y, wa.y, xaccA[r]);
                    xaccA[r] = fmaf(a.z, wa.z, xaccA[r]);
                    xaccA[r] = fmaf(a.w, wa.w, xaccA[r]);
                    xaccB[r] = fmaf(a.x, wb.x, xaccB[r]);
                    xaccB[r] = fmaf(a.y, wb.y, xaccB[r]);
                    xaccB[r] = fmaf(a.z, wb.z, xaccB[r]);
                    xaccB[r] = fmaf(a.w, wb.w, xaccB[r]);
                }
            }

            // ---- all-wave spin for h_t, then load own row ----
            const unsigned int target = 32u * (unsigned int)(t + 1);
            while (__hip_atomic_load(myctr, __ATOMIC_RELAXED,
                                     __HIP_MEMORY_SCOPE_AGENT) < target) {
                __builtin_amdgcn_s_sleep(1);
            }
            const float* hb = out + (size_t)t * BB * HH + (size_t)(row0 + wv) * HH;
            float4 ha, hb2;
            coh_load2_f4(hb + lane * 4, hb + 256 + lane * 4, ha, hb2);
            ((float4*)&hbuf[wv][0])[lane]      = ha;
            ((float4*)&hbuf[wv][0])[lane + 64] = hb2;
            __syncthreads();                   // S3
        }
    }
}

extern "C" void kernel_launch(void* const* d_in, const int* in_sizes, int n_in,
                              void* d_out, int out_size, void* d_ws, size_t ws_size,
                              hipStream_t stream) {
    const float* x  = (const float*)d_in[0];
    const float* Wi = (const float*)d_in[1];
    const float* Wh = (const float*)d_in[2];
    const float* bi = (const float*)d_in[3];
    const float* bh = (const float*)d_in[4];
    const float* h0 = (const float*)d_in[5];
    const float* c0 = (const float*)d_in[6];
    float* out = (float*)d_out;
    unsigned int* ctr = (unsigned int*)d_ws;   // 256 uints

    init_ctr<<<1, 256, 0, stream>>>(ctr);

    void* args[] = { (void*)&x, (void*)&Wi, (void*)&Wh, (void*)&bi,
                     (void*)&bh, (void*)&h0, (void*)&c0, (void*)&out,
                     (void*)&ctr };
    hipError_t e = hipLaunchCooperativeKernel((const void*)lstm_persist,
                                              dim3(NRG * NCG), dim3(THREADS),
                                              args, 0, stream);
    if (e != hipSuccess) {
        (void)hipGetLastError();
        lstm_persist<<<dim3(NRG * NCG), dim3(THREADS), 0, stream>>>(
            x, Wi, Wh, bi, bh, h0, c0, out, ctr);
    }
}

// Round 8
// 22016.725 us; speedup vs baseline: 1.0823x; 1.0823x over previous
//
#include <hip/hip_runtime.h>
#include <math.h>

// LSTM forward: T=1024, B=64, I=256, H=512 (4H=2048), fp32.
// Round 8: R6's verified tid0-spin sync + R7's software pipeline:
//   * x_{t+1} global-load issued before h-FMA (latency hidden), staged
//     conflict-free; x-partials computed in the arrive->spin window
//   * tid0-ONLY spin (R7's all-wave spin caused 47 GB of poll traffic ->
//     fabric congestion collapse; reverted)
//   * h exchange via inline-asm sc0 sc1 global ops (IF$ coherence point),
//     explicit s_waitcnt vmcnt(0) drain before arrive (R6-verified)
//   * 4 barriers/step; assembly merged into update; red padded to 68
// block = (rg: 8 rows) x (cg: 16 cells = 64 gate cols); 256 blocks x 512 thr.
// weights: 96 f32/thread in VGPRs; c LDS-resident; h chains through d_out.

#define TT      1024
#define BB      64
#define II      256
#define HH      512
#define G4H     2048
#define RPB     8
#define CPB     16
#define NCG     32
#define NRG     8
#define THREADS 512

__device__ __forceinline__ void coh_load2_f4(const float* p0, const float* p1,
                                             float4& a, float4& b) {
    asm volatile(
        "global_load_dwordx4 %0, %2, off sc0 sc1\n\t"
        "global_load_dwordx4 %1, %3, off sc0 sc1\n\t"
        "s_waitcnt vmcnt(0)"
        : "=&v"(a), "=&v"(b)
        : "v"(p0), "v"(p1)
        : "memory");
}
__device__ __forceinline__ void coh_store_f(float* p, float v) {
    asm volatile("global_store_dword %0, %1, off sc0 sc1"
                 :: "v"(p), "v"(v) : "memory");
}
__device__ __forceinline__ float fast_tanh(float v) {
    const float e = __expf(-2.0f * fabsf(v));
    const float r = (1.0f - e) / (1.0f + e);
    return v < 0.0f ? -r : r;
}

__global__ void init_ctr(unsigned int* ctr) { ctr[threadIdx.x] = 0; }

__global__ __launch_bounds__(THREADS, 2) void lstm_persist(
    const float* __restrict__ x,    // [T][B][I]
    const float* __restrict__ Wi,   // [I][4H]
    const float* __restrict__ Wh,   // [H][4H]
    const float* __restrict__ bi,   // [4H]
    const float* __restrict__ bh,   // [4H]
    const float* __restrict__ h0,   // [B][H]
    const float* __restrict__ c0,   // [B][H]
    float* __restrict__ out,        // [T][B][H]
    unsigned int* __restrict__ ctr) // [NRG*32], pre-zeroed
{
    const int tid   = threadIdx.x;
    const int cg    = blockIdx.x & 31;
    const int rg    = blockIdx.x >> 5;
    const int row0  = rg * RPB;
    const int cell0 = cg * CPB;

    const int lane   = tid & 63;
    const int wv     = tid >> 6;
    const int colgrp = lane & 31;
    const int kc     = wv * 2 + (lane >> 5);   // k chunk 0..15

    const int bcA = colgrp, bcB = colgrp + 32;
    const int JA  = (bcA >> 4) * HH + cell0 + (bcA & 15);
    const int JB  = (bcB >> 4) * HH + cell0 + (bcB & 15);

    __shared__ float xbuf[RPB][II];        // 8 KB
    __shared__ float hbuf[RPB][HH];        // 16 KB
    __shared__ float red[8][RPB][68];      // 17.4 KB (padded)
    __shared__ float c_lds[RPB][CPB];      // 512 B, persistent

    // ---- one-time: weights -> VGPRs (2 cols x (16 x-k + 32 h-k)) ----
    float4 wxA[4], wxB[4], whA[8], whB[8];
    #pragma unroll
    for (int q = 0; q < 4; ++q) {
        float ta[4], tb[4];
        #pragma unroll
        for (int e = 0; e < 4; ++e) {
            const int k = kc * 16 + q * 4 + e;
            ta[e] = Wi[(size_t)k * G4H + JA];
            tb[e] = Wi[(size_t)k * G4H + JB];
        }
        wxA[q] = make_float4(ta[0], ta[1], ta[2], ta[3]);
        wxB[q] = make_float4(tb[0], tb[1], tb[2], tb[3]);
    }
    #pragma unroll
    for (int q = 0; q < 8; ++q) {
        float ta[4], tb[4];
        #pragma unroll
        for (int e = 0; e < 4; ++e) {
            const int k = kc * 32 + q * 4 + e;
            ta[e] = Wh[(size_t)k * G4H + JA];
            tb[e] = Wh[(size_t)k * G4H + JB];
        }
        whA[q] = make_float4(ta[0], ta[1], ta[2], ta[3]);
        whB[q] = make_float4(tb[0], tb[1], tb[2], tb[3]);
    }

    // update-role constants (threads 0..127): r = tid>>4, m = tid&15
    float b4[4];
    if (tid < RPB * CPB) {
        const int m = tid & 15;
        #pragma unroll
        for (int G = 0; G < 4; ++G)
            b4[G] = bi[G * HH + cell0 + m] + bh[G * HH + cell0 + m];
        c_lds[tid >> 4][m] = c0[(size_t)(row0 + (tid >> 4)) * HH + cell0 + m];
    }

    unsigned int* myctr = ctr + rg * 32;

    // ---- prologue: stage x_0 and h0 (conflict-free), x-partials for t=0 ----
    {
        const float4 xv = ((const float4*)(x + (size_t)(row0 + wv) * II))[lane];
        ((float4*)&xbuf[wv][0])[lane] = xv;
        const float4* hs = (const float4*)(h0 + (size_t)(row0 + wv) * HH);
        ((float4*)&hbuf[wv][0])[lane]      = hs[lane];
        ((float4*)&hbuf[wv][0])[lane + 64] = hs[lane + 64];
    }
    __syncthreads();

    float xaccA[RPB], xaccB[RPB];
    {
        const float4* xv4 = ((const float4*)&xbuf[0][0]) + kc * 4;
        #pragma unroll
        for (int r = 0; r < RPB; ++r) { xaccA[r] = 0.f; xaccB[r] = 0.f; }
        #pragma unroll
        for (int q = 0; q < 4; ++q) {
            const float4 wa = wxA[q], wb = wxB[q];
            #pragma unroll
            for (int r = 0; r < RPB; ++r) {
                const float4 a = xv4[r * 64 + q];
                xaccA[r] = fmaf(a.x, wa.x, xaccA[r]);
                xaccA[r] = fmaf(a.y, wa.y, xaccA[r]);
                xaccA[r] = fmaf(a.z, wa.z, xaccA[r]);
                xaccA[r] = fmaf(a.w, wa.w, xaccA[r]);
                xaccB[r] = fmaf(a.x, wb.x, xaccB[r]);
                xaccB[r] = fmaf(a.y, wb.y, xaccB[r]);
                xaccB[r] = fmaf(a.z, wb.z, xaccB[r]);
                xaccB[r] = fmaf(a.w, wb.w, xaccB[r]);
            }
        }
    }
    __syncthreads();

    for (int t = 0; t < TT; ++t) {
        const bool more = (t + 1 < TT);

        // ---- issue x_{t+1} load early (hidden under h-FMA) ----
        float4 xnext;
        if (more)
            xnext = ((const float4*)(x + ((size_t)(t + 1) * BB + row0 + wv) * II))[lane];

        // ---- h-FMA: acc starts from x-partials ----
        float accA[RPB], accB[RPB];
        #pragma unroll
        for (int r = 0; r < RPB; ++r) { accA[r] = xaccA[r]; accB[r] = xaccB[r]; }
        {
            const float4* hv4 = ((const float4*)&hbuf[0][0]) + kc * 8;
            #pragma unroll
            for (int q = 0; q < 8; ++q) {
                const float4 wa = whA[q], wb = whB[q];
                #pragma unroll
                for (int r = 0; r < RPB; ++r) {
                    const float4 a = hv4[r * 128 + q];
                    accA[r] = fmaf(a.x, wa.x, accA[r]);
                    accA[r] = fmaf(a.y, wa.y, accA[r]);
                    accA[r] = fmaf(a.z, wa.z, accA[r]);
                    accA[r] = fmaf(a.w, wa.w, accA[r]);
                    accB[r] = fmaf(a.x, wb.x, accB[r]);
                    accB[r] = fmaf(a.y, wb.y, accB[r]);
                    accB[r] = fmaf(a.z, wb.z, accB[r]);
                    accB[r] = fmaf(a.w, wb.w, accB[r]);
                }
            }
        }

        // ---- stage x_{t+1} (conflict-free: lane -> f4 #lane) ----
        if (more) ((float4*)&xbuf[wv][0])[lane] = xnext;

        // ---- wave reduce (pair kc, kc^1 at lane^32) + red writes ----
        #pragma unroll
        for (int r = 0; r < RPB; ++r) {
            accA[r] += __shfl_xor(accA[r], 32, 64);
            accB[r] += __shfl_xor(accB[r], 32, 64);
        }
        if (lane < 32) {
            #pragma unroll
            for (int r = 0; r < RPB; ++r) {
                red[wv][r][colgrp]      = accA[r];
                red[wv][r][colgrp + 32] = accB[r];
            }
        }
        __syncthreads();                       // S1

        // ---- assembly + cell update (threads 0..127) ----
        if (tid < RPB * CPB) {
            const int r = tid >> 4, m = tid & 15;
            float gate[4];
            #pragma unroll
            for (int G = 0; G < 4; ++G) {
                float s = b4[G];
                #pragma unroll
                for (int p = 0; p < 8; ++p) s += red[p][r][G * 16 + m];
                gate[G] = s;
            }
            const float ig = 1.0f / (1.0f + __expf(-gate[0]));
            const float fg = 1.0f / (1.0f + __expf(-gate[1]));
            const float gg = fast_tanh(gate[2]);
            const float og = 1.0f / (1.0f + __expf(-gate[3]));
            const float cn = fg * c_lds[r][m] + ig * gg;
            c_lds[r][m] = cn;
            const size_t idx = ((size_t)t * BB + row0 + r) * HH + cell0 + m;
            coh_store_f(out + idx, og * fast_tanh(cn));
        }

        // ---- drain h stores, then arrive ----
        asm volatile("s_waitcnt vmcnt(0) lgkmcnt(0)" ::: "memory");
        __syncthreads();                       // S2
        if (more) {
            // arrive FIRST (peers can observe while we compute x-partials)
            if (tid == 0)
                __hip_atomic_fetch_add(myctr, 1u, __ATOMIC_RELAXED,
                                       __HIP_MEMORY_SCOPE_AGENT);

            // ---- x-partials for t+1: fills the arrive->ready window ----
            {
                const float4* xv4 = ((const float4*)&xbuf[0][0]) + kc * 4;
                #pragma unroll
                for (int r = 0; r < RPB; ++r) { xaccA[r] = 0.f; xaccB[r] = 0.f; }
                #pragma unroll
                for (int q = 0; q < 4; ++q) {
                    const float4 wa = wxA[q], wb = wxB[q];
                    #pragma unroll
                    for (int r = 0; r < RPB; ++r) {
                        const float4 a = xv4[r * 64 + q];
                        xaccA[r] = fmaf(a.x, wa.x, xaccA[r]);
                        xaccA[r] = fmaf(a.y, wa.y, xaccA[r]);
                        xaccA[r] = fmaf(a.z, wa.z, xaccA[r]);
                        xaccA[r] = fmaf(a.w, wa.w, xaccA[r]);
                        xaccB[r] = fmaf(a.x, wb.x, xaccB[r]);
                        xaccB[r] = fmaf(a.y, wb.y, xaccB[r]);
                        xaccB[r] = fmaf(a.z, wb.z, xaccB[r]);
                        xaccB[r] = fmaf(a.w, wb.w, xaccB[r]);
                    }
                }
            }

            // ---- tid0-ONLY spin (R6-proven; all-wave polling congests) ----
            if (tid == 0) {
                const unsigned int target = 32u * (unsigned int)(t + 1);
                while (__hip_atomic_load(myctr, __ATOMIC_RELAXED,
                                         __HIP_MEMORY_SCOPE_AGENT) < target) {
                    __builtin_amdgcn_s_sleep(2);
                }
            }
            __syncthreads();                   // S3

            // ---- load h_t: wave wv loads its own row, conflict-free ----
            const float* hb = out + (size_t)t * BB * HH + (size_t)(row0 + wv) * HH;
            float4 ha, hb2;
            coh_load2_f4(hb + lane * 4, hb + 256 + lane * 4, ha, hb2);
            ((float4*)&hbuf[wv][0])[lane]      = ha;
            ((float4*)&hbuf[wv][0])[lane + 64] = hb2;
            __syncthreads();                   // S4
        }
    }
}

extern "C" void kernel_launch(void* const* d_in, const int* in_sizes, int n_in,
                              void* d_out, int out_size, void* d_ws, size_t ws_size,
                              hipStream_t stream) {
    const float* x  = (const float*)d_in[0];
    const float* Wi = (const float*)d_in[1];
    const float* Wh = (const float*)d_in[2];
    const float* bi = (const float*)d_in[3];
    const float* bh = (const float*)d_in[4];
    const float* h0 = (const float*)d_in[5];
    const float* c0 = (const float*)d_in[6];
    float* out = (float*)d_out;
    unsigned int* ctr = (unsigned int*)d_ws;   // 256 uints

    init_ctr<<<1, 256, 0, stream>>>(ctr);

    void* args[] = { (void*)&x, (void*)&Wi, (void*)&Wh, (void*)&bi,
                     (void*)&bh, (void*)&h0, (void*)&c0, (void*)&out,
                     (void*)&ctr };
    hipError_t e = hipLaunchCooperativeKernel((const void*)lstm_persist,
                                              dim3(NRG * NCG), dim3(THREADS),
                                              args, 0, stream);
    if (e != hipSuccess) {
        (void)hipGetLastError();
        lstm_persist<<<dim3(NRG * NCG), dim3(THREADS), 0, stream>>>(
            x, Wi, Wh, bi, bh, h0, c0, out, ctr);
    }
}